// Round 11
// baseline (749.540 us; speedup 1.0000x reference)
//
#include <hip/hip_runtime.h>
#include <hip/hip_fp16.h>

// Problem constants (match reference)
constexpr int Nn   = 100000;   // nodes
constexpr int Ne   = 1600000;  // edges
constexpr int NF   = 16;       // input features
constexpr int HID  = 64;
constexpr int NOUT = 4;

// Bucket-sort CSR build params
constexpr int NBUK  = 391;
constexpr int CHUNK = 2048;
constexpr int NB1   = (Ne + CHUNK - 1) / CHUNK;  // 782
constexpr int NS    = NBUK * NB1;
constexpr int STASH = 6144;

union H8 { float4 f4; __half h[8]; };
union H4 { float2 f2; __half h[4]; };

typedef _Float16 f16x8 __attribute__((ext_vector_type(8)));
typedef float    f32x4 __attribute__((ext_vector_type(4)));

// Non-temporal 8B load (edge stream should not evict gather-table lines in L2)
#if defined(__has_builtin)
#if __has_builtin(__builtin_nontemporal_load)
#define NT_U64(p) __builtin_nontemporal_load((const unsigned long long*)(p))
#endif
#endif
#ifndef NT_U64
#define NT_U64(p) (*(const unsigned long long*)(p))
#endif

// ================= CSR build (atomic-free, 2-level bucket sort) =================

__global__ __launch_bounds__(256) void bhist_kernel(const int* __restrict__ dst,
                                                    int* __restrict__ ghist) {
    __shared__ int h[NBUK];
    int t = threadIdx.x;
    int b = blockIdx.x;
    for (int i = t; i < NBUK; i += 256) h[i] = 0;
    __syncthreads();
    int e0 = b * CHUNK;
    int e1 = (e0 + CHUNK < Ne) ? e0 + CHUNK : Ne;
    for (int e = e0 + t; e < e1; e += 256) atomicAdd(&h[dst[e] >> 8], 1);
    __syncthreads();
    for (int i = t; i < NBUK; i += 256) ghist[i * NB1 + b] = h[i];
}

__global__ __launch_bounds__(256) void scan1g_kernel(int* __restrict__ g,
                                                     int* __restrict__ bsum) {
    __shared__ int lds[256];
    int t = threadIdx.x;
    int base = blockIdx.x * 1024 + t * 4;
    int v0 = (base + 0 < NS) ? g[base + 0] : 0;
    int v1 = (base + 1 < NS) ? g[base + 1] : 0;
    int v2 = (base + 2 < NS) ? g[base + 2] : 0;
    int v3 = (base + 3 < NS) ? g[base + 3] : 0;
    lds[t] = v0 + v1 + v2 + v3;
    __syncthreads();
    for (int off = 1; off < 256; off <<= 1) {
        int a = lds[t];
        int b = (t >= off) ? lds[t - off] : 0;
        __syncthreads();
        lds[t] = a + b;
        __syncthreads();
    }
    int excl = (t > 0) ? lds[t - 1] : 0;
    if (base + 0 < NS) g[base + 0] = excl;
    if (base + 1 < NS) g[base + 1] = excl + v0;
    if (base + 2 < NS) g[base + 2] = excl + v0 + v1;
    if (base + 3 < NS) g[base + 3] = excl + v0 + v1 + v2;
    if (t == 255) bsum[blockIdx.x] = lds[255];
}

__global__ __launch_bounds__(512) void scan2g_kernel(int* __restrict__ bsum, int nb) {
    __shared__ int lds[512];
    int t = threadIdx.x;
    int v = (t < nb) ? bsum[t] : 0;
    lds[t] = v;
    __syncthreads();
    for (int off = 1; off < 512; off <<= 1) {
        int a = lds[t];
        int b = (t >= off) ? lds[t - off] : 0;
        __syncthreads();
        lds[t] = a + b;
        __syncthreads();
    }
    if (t < nb) bsum[t] = lds[t] - v;  // exclusive
}

__global__ __launch_bounds__(256) void scan3g_kernel(int* __restrict__ g,
                                                     const int* __restrict__ bsum) {
    int i = blockIdx.x * 256 + threadIdx.x;
    if (i < NS) g[i] += bsum[i >> 10];
}

__global__ __launch_bounds__(256) void bscatter_kernel(const int* __restrict__ src,
                                                       const int* __restrict__ dst,
                                                       const int* __restrict__ ghist,
                                                       int2* __restrict__ tmp) {
    __shared__ int hb[NBUK];
    __shared__ int cur[NBUK];
    int t = threadIdx.x;
    int b = blockIdx.x;
    for (int i = t; i < NBUK; i += 256) {
        hb[i] = ghist[i * NB1 + b];
        cur[i] = 0;
    }
    __syncthreads();
    int e0 = b * CHUNK;
    int e1 = (e0 + CHUNK < Ne) ? e0 + CHUNK : Ne;
    for (int e = e0 + t; e < e1; e += 256) {
        int d = dst[e];
        int s = src[e];
        int bin = d >> 8;
        int r = atomicAdd(&cur[bin], 1);
        tmp[hb[bin] + r] = make_int2(s, d);
    }
}

__global__ __launch_bounds__(256) void bcsr_kernel(const int2* __restrict__ tmp,
                                                   const int* __restrict__ ghist,
                                                   int* __restrict__ rowptr,
                                                   float* __restrict__ dinv,
                                                   int* __restrict__ colsrc) {
    __shared__ int2 stash[STASH];
    __shared__ int h[256];
    __shared__ int hs[256];
    __shared__ int cur[256];
    int t = threadIdx.x;
    int b = blockIdx.x;
    int lo = ghist[b * NB1];
    int hi = (b < NBUK - 1) ? ghist[(b + 1) * NB1] : Ne;
    int sz = hi - lo;
    h[t] = 0;
    cur[t] = 0;
    __syncthreads();
    for (int i = t; i < sz; i += 256) {
        int2 rec = tmp[lo + i];
        if (i < STASH) stash[i] = rec;
        atomicAdd(&h[rec.y & 255], 1);
    }
    __syncthreads();
    int myh = h[t];
    hs[t] = myh;
    __syncthreads();
    for (int off = 1; off < 256; off <<= 1) {
        int a = hs[t];
        int bb = (t >= off) ? hs[t - off] : 0;
        __syncthreads();
        hs[t] = a + bb;
        __syncthreads();
    }
    int excl = hs[t] - myh;
    __syncthreads();
    hs[t] = excl;
    int d = (b << 8) + t;
    if (d < Nn) {
        rowptr[d] = lo + excl;
        dinv[d] = (myh > 0) ? rsqrtf((float)myh) : 0.0f;
    }
    if (b == NBUK - 1 && t == 0) rowptr[Nn] = Ne;
    __syncthreads();
    for (int i = t; i < sz; i += 256) {
        int2 rec = (i < STASH) ? stash[i] : tmp[lo + i];
        int bin = rec.y & 255;
        int r = atomicAdd(&cur[bin], 1);
        colsrc[lo + hs[bin] + r] = rec.x;
    }
}

__global__ __launch_bounds__(256) void fill_kernel(const int* __restrict__ colsrc,
                                                   const float* __restrict__ dinv,
                                                   int2* __restrict__ edge2) {
    int e = blockIdx.x * 256 + threadIdx.x;
    if (e < Ne) {
        int s = colsrc[e];
        edge2[e] = make_int2(s, __float_as_int(dinv[s]));
    }
}

// x[N,16] f32 -> xh[N,16] fp16
__global__ __launch_bounds__(256) void xcvt_kernel(const float* __restrict__ x,
                                                   __half* __restrict__ xh) {
    int i = blockIdx.x * 256 + threadIdx.x;
    if (i < Nn * NF / 4) {
        float4 v = reinterpret_cast<const float4*>(x)[i];
        H4 o;
        o.h[0] = __float2half(v.x);
        o.h[1] = __float2half(v.y);
        o.h[2] = __float2half(v.z);
        o.h[3] = __float2half(v.w);
        reinterpret_cast<float2*>(xh)[i] = o.f2;
    }
}

// ================= pull-mode propagation (fp16 tables, f32 math) =================

// F=64, PLANE-SPLIT: each pass covers 32 halves (64B rows = one cache line), so the
// per-pass gather working set (6.4 MB) nearly fits one XCD L2 (4 MB): capacity-miss
// bytes drop ~3.7x vs the 128B-row single pass. 4 nodes/wave, 4 lanes/row (16B each),
// 4 edges in flight, 2-deep pipeline, nt edge stream.
__global__ __launch_bounds__(256) void pull64p_kernel(const __half* __restrict__ hin,
                                                      const int* __restrict__ rowptr,
                                                      const int2* __restrict__ edge2,
                                                      const float* __restrict__ dinv,
                                                      __half* __restrict__ hout,
                                                      int plane) {
    int lane = threadIdx.x & 63;
    int q  = lane & 3;          // 8-half chunk within the 32-half plane
    int eo = (lane >> 2) & 3;   // edge slot
    int g  = lane >> 4;         // node sub-index
    int n = blockIdx.x * 16 + (threadIdx.x >> 6) * 4 + g;
    if (n >= Nn) return;
    const __half* hp = hin + plane * 32 + q * 8;
    int r0 = rowptr[n];
    int r1 = rowptr[n + 1];
    float a[8];
#pragma unroll
    for (int j = 0; j < 8; ++j) a[j] = 0.f;

    int e = r0 + eo;
    unsigned long long ed0 = (e < r1) ? NT_U64(&edge2[e]) : 0ull;
    unsigned long long ed1 = (e + 4 < r1) ? NT_U64(&edge2[e + 4]) : 0ull;
    float4 ga = *reinterpret_cast<const float4*>(hp + (size_t)(unsigned)(ed0 & 0xffffffffu) * 64);
#pragma unroll 1
    for (; e < r1; e += 4) {
        unsigned long long ed2 = (e + 8 < r1) ? NT_U64(&edge2[e + 8]) : 0ull;
        float4 na = *reinterpret_cast<const float4*>(hp + (size_t)(unsigned)(ed1 & 0xffffffffu) * 64);
        float w = __int_as_float((int)(ed0 >> 32));
        H8 u;
        u.f4 = ga;
#pragma unroll
        for (int j = 0; j < 8; ++j) a[j] += w * __half2float(u.h[j]);
        ed0 = ed1; ed1 = ed2; ga = na;
    }
#pragma unroll
    for (int off = 4; off <= 8; off <<= 1)
#pragma unroll
        for (int j = 0; j < 8; ++j) a[j] += __shfl_xor(a[j], off);
    if (eo == 0) {
        float dn = dinv[n];
        H8 o;
#pragma unroll
        for (int j = 0; j < 8; ++j) o.h[j] = __float2half(a[j] * dn);
        *reinterpret_cast<float4*>(hout + (size_t)n * 64 + plane * 32 + q * 8) = o.f4;
    }
}

// F=16: 8 nodes per wave (8 lanes each); table 3.2 MB fits L2 — no split needed.
__global__ __launch_bounds__(256) void pull16h_kernel(const __half* __restrict__ hin,
                                                      const int* __restrict__ rowptr,
                                                      const int2* __restrict__ edge2,
                                                      const float* __restrict__ dinv,
                                                      __half* __restrict__ hout) {
    int lane = threadIdx.x & 63;
    int q  = lane & 1;
    int eo = (lane >> 1) & 3;
    int g  = lane >> 3;
    int n = blockIdx.x * 32 + (threadIdx.x >> 6) * 8 + g;
    if (n >= Nn) return;
    int r0 = rowptr[n];
    int r1 = rowptr[n + 1];
    float a[8];
#pragma unroll
    for (int j = 0; j < 8; ++j) a[j] = 0.f;

    int e = r0 + eo;
    unsigned long long ed0 = (e < r1) ? NT_U64(&edge2[e]) : 0ull;
    unsigned long long ed1 = (e + 4 < r1) ? NT_U64(&edge2[e + 4]) : 0ull;
    float4 ga = *reinterpret_cast<const float4*>(hin + (size_t)(unsigned)(ed0 & 0xffffffffu) * 16 + q * 8);
#pragma unroll 1
    for (; e < r1; e += 4) {
        unsigned long long ed2 = (e + 8 < r1) ? NT_U64(&edge2[e + 8]) : 0ull;
        float4 na = *reinterpret_cast<const float4*>(hin + (size_t)(unsigned)(ed1 & 0xffffffffu) * 16 + q * 8);
        float w = __int_as_float((int)(ed0 >> 32));
        H8 u;
        u.f4 = ga;
#pragma unroll
        for (int j = 0; j < 8; ++j) a[j] += w * __half2float(u.h[j]);
        ed0 = ed1; ed1 = ed2; ga = na;
    }
#pragma unroll
    for (int off = 2; off <= 4; off <<= 1)
#pragma unroll
        for (int j = 0; j < 8; ++j) a[j] += __shfl_xor(a[j], off);
    if (eo == 0) {
        float dn = dinv[n];
        H8 o;
#pragma unroll
        for (int j = 0; j < 8; ++j) o.h[j] = __float2half(a[j] * dn);
        *reinterpret_cast<float4*>(hout + (size_t)n * 16 + q * 8) = o.f4;
    }
}

// width-4 pull with fused add (f32 tables, 1.6 MB — fits L2), 2-deep pipeline
template <int ADDBIAS>
__global__ __launch_bounds__(256) void pull4_kernel(const float* __restrict__ uin,
                                                    const float* __restrict__ gadd,
                                                    const int* __restrict__ rowptr,
                                                    const int2* __restrict__ edge2,
                                                    const float* __restrict__ dinv,
                                                    const float* __restrict__ beff,
                                                    float* __restrict__ out) {
    int lane = threadIdx.x & 63;
    int eo = lane & 15;
    int n = blockIdx.x * 16 + ((threadIdx.x >> 6) << 2) + (lane >> 4);
    if (n >= Nn) return;
    int r0 = rowptr[n];
    int r1 = rowptr[n + 1];
    float ax = 0.f, ay = 0.f, az = 0.f, aw = 0.f;

    int e = r0 + eo;
    unsigned long long ed0 = (e < r1) ? NT_U64(&edge2[e]) : 0ull;
    unsigned long long ed1 = (e + 16 < r1) ? NT_U64(&edge2[e + 16]) : 0ull;
    float4 ga = *reinterpret_cast<const float4*>(uin + (size_t)(unsigned)(ed0 & 0xffffffffu) * 4);
#pragma unroll 1
    for (; e < r1; e += 16) {
        unsigned long long ed2 = (e + 32 < r1) ? NT_U64(&edge2[e + 32]) : 0ull;
        float4 na = *reinterpret_cast<const float4*>(uin + (size_t)(unsigned)(ed1 & 0xffffffffu) * 4);
        float w = __int_as_float((int)(ed0 >> 32));
        ax += w * ga.x;
        ay += w * ga.y;
        az += w * ga.z;
        aw += w * ga.w;
        ed0 = ed1; ed1 = ed2; ga = na;
    }
#pragma unroll
    for (int off = 1; off < 16; off <<= 1) {
        ax += __shfl_xor(ax, off);
        ay += __shfl_xor(ay, off);
        az += __shfl_xor(az, off);
        aw += __shfl_xor(aw, off);
    }
    if (eo == 0) {
        float dn = dinv[n];
        float4 g = *reinterpret_cast<const float4*>(gadd + (size_t)n * 4);
        float4 o;
        o.x = g.x + dn * ax;
        o.y = g.y + dn * ay;
        o.z = g.z + dn * az;
        o.w = g.w + dn * aw;
        if (ADDBIAS) {
            o.x += beff[0]; o.y += beff[1]; o.z += beff[2]; o.w += beff[3];
        }
        *reinterpret_cast<float4*>(out + (size_t)n * 4) = o;
    }
}

// ================= weight fragment prep =================
template <int KS>
__global__ __launch_bounds__(256) void wfrag_kernel(const float* __restrict__ W,  // [4][KS][64]
                                                    __half* __restrict__ Wfrag) {
    constexpr int NT = (4 * KS / 32) * 4 * 64;
    int tid = blockIdx.x * 256 + threadIdx.x;
    if (tid >= NT) return;
    int l  = tid & 63;
    int ct = (tid >> 6) & 3;
    int ks = tid >> 8;
    int c  = ct * 16 + (l & 15);
    int kb = ks * 32 + (l >> 4) * 8;
    H8 o;
#pragma unroll
    for (int j = 0; j < 8; ++j) {
        int k = kb + j;
        o.h[j] = __float2half(W[(size_t)(k / KS) * KS * 64 + (size_t)(k % KS) * 64 + c]);
    }
    *reinterpret_cast<float4*>(Wfrag + (size_t)tid * 8) = o.f4;
}

// ================= fused 4-source MFMA GEMM =================
template <int KS, int RELU>
__global__ __launch_bounds__(256) void gemm4m_kernel(const __half* __restrict__ S0,
                                                     const __half* __restrict__ S1,
                                                     const __half* __restrict__ S2,
                                                     const __half* __restrict__ S3,
                                                     const __half* __restrict__ Wfrag,
                                                     const float* __restrict__ bias,
                                                     __half* __restrict__ out) {
    constexpr int NKS = 4 * KS / 32;  // K-steps of 32
    int lane = threadIdx.x & 63;
    int wv = threadIdx.x >> 6;
    int base = blockIdx.x * 128 + wv * 32;
    int r = lane & 15;
    int qa = lane >> 4;
    int acol = qa * 8;
    const __half* Ss[4] = {S0, S1, S2, S3};
    f32x4 acc[2][4] = {};
    int row0 = base + r;       if (row0 >= Nn) row0 = Nn - 1;
    int row1 = base + 16 + r;  if (row1 >= Nn) row1 = Nn - 1;
#pragma unroll
    for (int ks = 0; ks < NKS; ++ks) {
        int k0 = ks * 32 + acol;
        const __half* Sa = Ss[k0 / KS];
        int col = k0 % KS;
        f16x8 a0 = *reinterpret_cast<const f16x8*>(Sa + (size_t)row0 * KS + col);
        f16x8 a1 = *reinterpret_cast<const f16x8*>(Sa + (size_t)row1 * KS + col);
        const __half* wp = Wfrag + ((size_t)(ks * 4) * 64 + lane) * 8;
#pragma unroll
        for (int ct = 0; ct < 4; ++ct) {
            f16x8 b = *reinterpret_cast<const f16x8*>(wp + (size_t)ct * 64 * 8);
            acc[0][ct] = __builtin_amdgcn_mfma_f32_16x16x32_f16(a0, b, acc[0][ct], 0, 0, 0);
            acc[1][ct] = __builtin_amdgcn_mfma_f32_16x16x32_f16(a1, b, acc[1][ct], 0, 0, 0);
        }
    }
    int ccol = lane & 15;
    int rb = (lane >> 4) * 4;
#pragma unroll
    for (int rt = 0; rt < 2; ++rt) {
#pragma unroll
        for (int ct = 0; ct < 4; ++ct) {
            float bi = bias[ct * 16 + ccol];
#pragma unroll
            for (int i = 0; i < 4; ++i) {
                int row = base + rt * 16 + rb + i;
                if (row < Nn) {
                    float v = acc[rt][ct][i] + bi;
                    if (RELU) v = fmaxf(v, 0.f);
                    out[(size_t)row * 64 + ct * 16 + ccol] = __float2half(v);
                }
            }
        }
    }
}

// ================= last conv + FC folding =================
__global__ __launch_bounds__(256) void weff_kernel(const float* __restrict__ W,   // Wh[2]: [4][64][64]
                                                   const float* __restrict__ b,   // bh[2]: [64]
                                                   const float* __restrict__ fcW, // [64][4]
                                                   const float* __restrict__ fcb, // [4]
                                                   float* __restrict__ Wg,        // [4][64][4]
                                                   float* __restrict__ beff) {    // [4]
    int t = threadIdx.x;  // t = k*64 + c
    int k = t >> 6, c = t & 63;
    const float* wrow = W + (size_t)t * 64;
    float a0 = 0.f, a1 = 0.f, a2 = 0.f, a3 = 0.f;
    for (int d = 0; d < 64; ++d) {
        float w = wrow[d];
        a0 += w * fcW[d * 4 + 0];
        a1 += w * fcW[d * 4 + 1];
        a2 += w * fcW[d * 4 + 2];
        a3 += w * fcW[d * 4 + 3];
    }
    float4 o; o.x = a0; o.y = a1; o.z = a2; o.w = a3;
    *reinterpret_cast<float4*>(Wg + k * 256 + c * 4) = o;
    if (t < 4) {
        float s = fcb[t];
        for (int d = 0; d < 64; ++d) s += b[d] * fcW[d * 4 + t];
        beff[t] = s;
    }
}

// Gk[n][j] = sum_c h[n][c] * Wg[k][c][j]
__global__ __launch_bounds__(256) void gemmG_kernel(const __half* __restrict__ h,
                                                    const float* __restrict__ Wg,
                                                    float* __restrict__ G) {
    __shared__ float Ht[64 * 65];
    __shared__ float Wl[1024];
    int t = threadIdx.x;
    int r0 = blockIdx.x * 64;
    for (int i = t; i < 256; i += 256)
        *reinterpret_cast<float4*>(&Wl[i * 4]) = *reinterpret_cast<const float4*>(Wg + i * 4);
    for (int i = t; i < 64 * 8; i += 256) {
        int r = i >> 3;
        int c8 = i & 7;
        int row = r0 + r;
        float* hp = &Ht[r * 65 + c8 * 8];
        if (row < Nn) {
            H8 u;
            u.f4 = *reinterpret_cast<const float4*>(h + (size_t)row * 64 + c8 * 8);
#pragma unroll
            for (int j = 0; j < 8; ++j) hp[j] = __half2float(u.h[j]);
        } else {
#pragma unroll
            for (int j = 0; j < 8; ++j) hp[j] = 0.f;
        }
    }
    __syncthreads();
    int r = t & 63;
    int k = t >> 6;
    float a0 = 0.f, a1 = 0.f, a2 = 0.f, a3 = 0.f;
#pragma unroll 8
    for (int c = 0; c < 64; ++c) {
        float hv = Ht[r * 65 + c];
        const float* wp = &Wl[k * 256 + c * 4];
        a0 += hv * wp[0];
        a1 += hv * wp[1];
        a2 += hv * wp[2];
        a3 += hv * wp[3];
    }
    int row = r0 + r;
    if (row < Nn) {
        float4 o; o.x = a0; o.y = a1; o.z = a2; o.w = a3;
        *reinterpret_cast<float4*>(G + (size_t)k * Nn * 4 + (size_t)row * 4) = o;
    }
}

// ================= host driver =================

extern "C" void kernel_launch(void* const* d_in, const int* in_sizes, int n_in,
                              void* d_out, int out_size, void* d_ws, size_t ws_size,
                              hipStream_t stream) {
    const float* x   = (const float*)d_in[0];
    const int*   ei  = (const int*)d_in[1];   // [2, E] int32
    const float* W0  = (const float*)d_in[2]; // [4,16,64]
    const float* b0  = (const float*)d_in[3]; // [64]
    const float* Wh  = (const float*)d_in[4]; // [3,4,64,64]
    const float* bh  = (const float*)d_in[5]; // [3,64]
    const float* fcW = (const float*)d_in[6]; // [64,4]
    const float* fcb = (const float*)d_in[7]; // [4]
    float* out = (float*)d_out;

    const int* src = ei;
    const int* dst = ei + Ne;

    // ws layout:
    // rowptr[100004] | edge2[2E] | ghist[305792] | bsum[512] | dinv[N] | Wg[1024] | beff[16]
    // | Wf0[4096]h | Wf1[16384]h | Wf2[16384]h | xh[N*16]h | H0..H3[N*64]h | G(6*N*4 f32)
    int*    rowptr = (int*)d_ws;
    int2*   edge2  = (int2*)(rowptr + 100004);
    int*    ghist  = (int*)(rowptr + 100004 + 2 * Ne);
    int*    bsum   = ghist + 305792;
    float*  dinv   = (float*)(bsum + 512);
    float*  Wg     = dinv + Nn;
    float*  beff   = Wg + 1024;
    __half* Wf0    = (__half*)(beff + 16);
    __half* Wf1    = Wf0 + 4096;
    __half* Wf2    = Wf1 + 16384;
    __half* xh     = Wf2 + 16384;
    __half* H0     = xh + (size_t)Nn * NF;
    __half* H1     = H0 + (size_t)Nn * HID;
    __half* H2     = H1 + (size_t)Nn * HID;
    __half* H3     = H2 + (size_t)Nn * HID;
    float*  G      = (float*)(H3 + (size_t)Nn * HID);
    float*  G0     = G + 0 * (size_t)Nn * 4;
    float*  G1     = G + 1 * (size_t)Nn * 4;
    float*  G2     = G + 2 * (size_t)Nn * 4;
    float*  G3     = G + 3 * (size_t)Nn * 4;
    float*  T      = G + 4 * (size_t)Nn * 4;
    float*  T2     = G + 5 * (size_t)Nn * 4;
    int2*   tmp    = (int2*)H2;   // 12.8 MB, dead after bcsr
    int*    colsrc = (int*)H1;    // 6.4 MB, dead after fill

    const int egrid  = (Ne + 255) / 256;           // 6250
    const int s1grid = (NS + 1023) / 1024;         // 299
    const int s3grid = (NS + 255) / 256;           // 1195
    const int p64grid = (Nn + 15) / 16;            // 6250
    const int p16grid = (Nn + 31) / 32;            // 3125
    const int ggrid  = (Nn + 127) / 128;           // 782
    const int qgrid  = (Nn + 15) / 16;             // 6250
    const int Ggrid  = (Nn + 63) / 64;             // 1563
    const int cgrid  = (Nn * NF / 4 + 255) / 256;

    // --- CSR build: bucket sort, no global atomics ---
    bhist_kernel<<<NB1, 256, 0, stream>>>(dst, ghist);
    scan1g_kernel<<<s1grid, 256, 0, stream>>>(ghist, bsum);
    scan2g_kernel<<<1, 512, 0, stream>>>(bsum, s1grid);
    scan3g_kernel<<<s3grid, 256, 0, stream>>>(ghist, bsum);
    bscatter_kernel<<<NB1, 256, 0, stream>>>(src, dst, ghist, tmp);
    bcsr_kernel<<<NBUK, 256, 0, stream>>>(tmp, ghist, rowptr, dinv, colsrc);
    fill_kernel<<<egrid, 256, 0, stream>>>(colsrc, dinv, edge2);
    weff_kernel<<<1, 256, 0, stream>>>(Wh + 2 * 4 * 64 * 64, bh + 2 * 64, fcW, fcb, Wg, beff);
    xcvt_kernel<<<cgrid, 256, 0, stream>>>(x, xh);
    wfrag_kernel<16><<<2, 256, 0, stream>>>(W0, Wf0);
    wfrag_kernel<64><<<8, 256, 0, stream>>>(Wh + 0 * 4 * 64 * 64, Wf1);
    wfrag_kernel<64><<<8, 256, 0, stream>>>(Wh + 1 * 4 * 64 * 64, Wf2);

    // --- conv0 (F=16 hops, relu) -> H0 ---
    pull16h_kernel<<<p16grid, 256, 0, stream>>>(xh, rowptr, edge2, dinv, H1);
    pull16h_kernel<<<p16grid, 256, 0, stream>>>(H1, rowptr, edge2, dinv, H2);
    pull16h_kernel<<<p16grid, 256, 0, stream>>>(H2, rowptr, edge2, dinv, H3);
    gemm4m_kernel<16, 1><<<ggrid, 256, 0, stream>>>(xh, H1, H2, H3, Wf0, b0, H0);

    // --- conv1, conv2 (relu) : H0 -> H0, plane-split hops ---
    for (int l = 0; l < 2; ++l) {
        pull64p_kernel<<<p64grid, 256, 0, stream>>>(H0, rowptr, edge2, dinv, H1, 0);
        pull64p_kernel<<<p64grid, 256, 0, stream>>>(H0, rowptr, edge2, dinv, H1, 1);
        pull64p_kernel<<<p64grid, 256, 0, stream>>>(H1, rowptr, edge2, dinv, H2, 0);
        pull64p_kernel<<<p64grid, 256, 0, stream>>>(H1, rowptr, edge2, dinv, H2, 1);
        pull64p_kernel<<<p64grid, 256, 0, stream>>>(H2, rowptr, edge2, dinv, H3, 0);
        pull64p_kernel<<<p64grid, 256, 0, stream>>>(H2, rowptr, edge2, dinv, H3, 1);
        gemm4m_kernel<64, 1><<<ggrid, 256, 0, stream>>>(H0, H1, H2, H3,
                                                        (l == 0) ? Wf1 : Wf2,
                                                        bh + (size_t)l * HID, H0);
    }

    // --- conv3 + FC, folded to width 4 + Horner (f32 chain) ---
    // out = G0 + A(G1 + A(G2 + A*G3)) + beff
    gemmG_kernel<<<Ggrid, 256, 0, stream>>>(H0, Wg, G);
    pull4_kernel<0><<<qgrid, 256, 0, stream>>>(G3, G2, rowptr, edge2, dinv, beff, T);
    pull4_kernel<0><<<qgrid, 256, 0, stream>>>(T,  G1, rowptr, edge2, dinv, beff, T2);
    pull4_kernel<1><<<qgrid, 256, 0, stream>>>(T2, G0, rowptr, edge2, dinv, beff, out);
}

// Round 12
// 533.132 us; speedup vs baseline: 1.4059x; 1.4059x over previous
//
#include <hip/hip_runtime.h>
#include <hip/hip_fp16.h>

// Problem constants (match reference)
constexpr int Nn   = 100000;   // nodes
constexpr int Ne   = 1600000;  // edges
constexpr int NF   = 16;       // input features
constexpr int HID  = 64;
constexpr int NOUT = 4;

// Bucket-sort CSR build params
constexpr int NBUK  = 391;
constexpr int CHUNK = 2048;
constexpr int NB1   = (Ne + CHUNK - 1) / CHUNK;  // 782
constexpr int NS    = NBUK * NB1;
constexpr int STASH = 6144;

union H8 { float4 f4; __half h[8]; };
union H4 { float2 f2; __half h[4]; };

typedef _Float16 f16x8 __attribute__((ext_vector_type(8)));
typedef float    f32x4 __attribute__((ext_vector_type(4)));

// ================= CSR build (atomic-free, 2-level bucket sort) =================

__global__ __launch_bounds__(256) void bhist_kernel(const int* __restrict__ dst,
                                                    int* __restrict__ ghist) {
    __shared__ int h[NBUK];
    int t = threadIdx.x;
    int b = blockIdx.x;
    for (int i = t; i < NBUK; i += 256) h[i] = 0;
    __syncthreads();
    int e0 = b * CHUNK;
    int e1 = (e0 + CHUNK < Ne) ? e0 + CHUNK : Ne;
    for (int e = e0 + t; e < e1; e += 256) atomicAdd(&h[dst[e] >> 8], 1);
    __syncthreads();
    for (int i = t; i < NBUK; i += 256) ghist[i * NB1 + b] = h[i];
}

__global__ __launch_bounds__(256) void scan1g_kernel(int* __restrict__ g,
                                                     int* __restrict__ bsum) {
    __shared__ int lds[256];
    int t = threadIdx.x;
    int base = blockIdx.x * 1024 + t * 4;
    int v0 = (base + 0 < NS) ? g[base + 0] : 0;
    int v1 = (base + 1 < NS) ? g[base + 1] : 0;
    int v2 = (base + 2 < NS) ? g[base + 2] : 0;
    int v3 = (base + 3 < NS) ? g[base + 3] : 0;
    lds[t] = v0 + v1 + v2 + v3;
    __syncthreads();
    for (int off = 1; off < 256; off <<= 1) {
        int a = lds[t];
        int b = (t >= off) ? lds[t - off] : 0;
        __syncthreads();
        lds[t] = a + b;
        __syncthreads();
    }
    int excl = (t > 0) ? lds[t - 1] : 0;
    if (base + 0 < NS) g[base + 0] = excl;
    if (base + 1 < NS) g[base + 1] = excl + v0;
    if (base + 2 < NS) g[base + 2] = excl + v0 + v1;
    if (base + 3 < NS) g[base + 3] = excl + v0 + v1 + v2;
    if (t == 255) bsum[blockIdx.x] = lds[255];
}

__global__ __launch_bounds__(512) void scan2g_kernel(int* __restrict__ bsum, int nb) {
    __shared__ int lds[512];
    int t = threadIdx.x;
    int v = (t < nb) ? bsum[t] : 0;
    lds[t] = v;
    __syncthreads();
    for (int off = 1; off < 512; off <<= 1) {
        int a = lds[t];
        int b = (t >= off) ? lds[t - off] : 0;
        __syncthreads();
        lds[t] = a + b;
        __syncthreads();
    }
    if (t < nb) bsum[t] = lds[t] - v;  // exclusive
}

__global__ __launch_bounds__(256) void scan3g_kernel(int* __restrict__ g,
                                                     const int* __restrict__ bsum) {
    int i = blockIdx.x * 256 + threadIdx.x;
    if (i < NS) g[i] += bsum[i >> 10];
}

__global__ __launch_bounds__(256) void bscatter_kernel(const int* __restrict__ src,
                                                       const int* __restrict__ dst,
                                                       const int* __restrict__ ghist,
                                                       int2* __restrict__ tmp) {
    __shared__ int hb[NBUK];
    __shared__ int cur[NBUK];
    int t = threadIdx.x;
    int b = blockIdx.x;
    for (int i = t; i < NBUK; i += 256) {
        hb[i] = ghist[i * NB1 + b];
        cur[i] = 0;
    }
    __syncthreads();
    int e0 = b * CHUNK;
    int e1 = (e0 + CHUNK < Ne) ? e0 + CHUNK : Ne;
    for (int e = e0 + t; e < e1; e += 256) {
        int d = dst[e];
        int s = src[e];
        int bin = d >> 8;
        int r = atomicAdd(&cur[bin], 1);
        tmp[hb[bin] + r] = make_int2(s, d);
    }
}

// K2: one block per bucket -> rowptr, dinv, and final 4B-src CSR (ecol)
__global__ __launch_bounds__(256) void bcsr_kernel(const int2* __restrict__ tmp,
                                                   const int* __restrict__ ghist,
                                                   int* __restrict__ rowptr,
                                                   float* __restrict__ dinv,
                                                   int* __restrict__ ecol) {
    __shared__ int2 stash[STASH];
    __shared__ int h[256];
    __shared__ int hs[256];
    __shared__ int cur[256];
    int t = threadIdx.x;
    int b = blockIdx.x;
    int lo = ghist[b * NB1];
    int hi = (b < NBUK - 1) ? ghist[(b + 1) * NB1] : Ne;
    int sz = hi - lo;
    h[t] = 0;
    cur[t] = 0;
    __syncthreads();
    for (int i = t; i < sz; i += 256) {
        int2 rec = tmp[lo + i];
        if (i < STASH) stash[i] = rec;
        atomicAdd(&h[rec.y & 255], 1);
    }
    __syncthreads();
    int myh = h[t];
    hs[t] = myh;
    __syncthreads();
    for (int off = 1; off < 256; off <<= 1) {
        int a = hs[t];
        int bb = (t >= off) ? hs[t - off] : 0;
        __syncthreads();
        hs[t] = a + bb;
        __syncthreads();
    }
    int excl = hs[t] - myh;
    __syncthreads();
    hs[t] = excl;
    int d = (b << 8) + t;
    if (d < Nn) {
        rowptr[d] = lo + excl;
        dinv[d] = (myh > 0) ? rsqrtf((float)myh) : 0.0f;
    }
    if (b == NBUK - 1 && t == 0) rowptr[Nn] = Ne;
    __syncthreads();
    for (int i = t; i < sz; i += 256) {
        int2 rec = (i < STASH) ? stash[i] : tmp[lo + i];
        int bin = rec.y & 255;
        int r = atomicAdd(&cur[bin], 1);
        ecol[lo + hs[bin] + r] = rec.x;
    }
}

// x[N,16] f32 -> xh[N,16] fp16
__global__ __launch_bounds__(256) void xcvt_kernel(const float* __restrict__ x,
                                                   __half* __restrict__ xh) {
    int i = blockIdx.x * 256 + threadIdx.x;
    if (i < Nn * NF / 4) {
        float4 v = reinterpret_cast<const float4*>(x)[i];
        H4 o;
        o.h[0] = __float2half(v.x);
        o.h[1] = __float2half(v.y);
        o.h[2] = __float2half(v.z);
        o.h[3] = __float2half(v.w);
        reinterpret_cast<float2*>(xh)[i] = o.f2;
    }
}

// ================= pull-mode propagation (fp16 tables, f32 math) =================
// 4B edge records (src only); w = dinv[s] gathered from the 400 KB L2-resident table.
// 2-deep software pipeline; dummy slots use s=0 with explicit w=0.

// F=64: 4 nodes per wave (16 lanes each); 4 lanes/row (16B each); 4 edges in flight.
__global__ __launch_bounds__(256) void pull64h_kernel(const __half* __restrict__ hin,
                                                      const int* __restrict__ rowptr,
                                                      const int* __restrict__ ecol,
                                                      const float* __restrict__ dinv,
                                                      __half* __restrict__ hout) {
    int lane = threadIdx.x & 63;
    int q  = lane & 3;
    int eo = (lane >> 2) & 3;
    int g  = lane >> 4;
    int n = blockIdx.x * 16 + (threadIdx.x >> 6) * 4 + g;
    if (n >= Nn) return;
    int r0 = rowptr[n];
    int r1 = rowptr[n + 1];
    float a[16];
#pragma unroll
    for (int j = 0; j < 16; ++j) a[j] = 0.f;

    int e = r0 + eo;
    int s0 = (e < r1) ? ecol[e] : 0;
    float w0 = (e < r1) ? dinv[s0] : 0.f;
    int s1 = (e + 4 < r1) ? ecol[e + 4] : 0;
    float w1 = (e + 4 < r1) ? dinv[s1] : 0.f;
    const float4* rp0 = reinterpret_cast<const float4*>(hin + (size_t)s0 * 64 + q * 16);
    float4 ga = rp0[0], gb = rp0[1];
#pragma unroll 1
    for (; e < r1; e += 4) {
        int s2 = (e + 8 < r1) ? ecol[e + 8] : 0;
        float w2 = (e + 8 < r1) ? dinv[s2] : 0.f;
        const float4* rp1 = reinterpret_cast<const float4*>(hin + (size_t)s1 * 64 + q * 16);
        float4 na = rp1[0], nb = rp1[1];
        H8 u0, u1;
        u0.f4 = ga;
        u1.f4 = gb;
#pragma unroll
        for (int j = 0; j < 8; ++j) a[j] += w0 * __half2float(u0.h[j]);
#pragma unroll
        for (int j = 0; j < 8; ++j) a[8 + j] += w0 * __half2float(u1.h[j]);
        s1 = s2; w0 = w1; w1 = w2; ga = na; gb = nb;
    }
#pragma unroll
    for (int off = 4; off <= 8; off <<= 1)
#pragma unroll
        for (int j = 0; j < 16; ++j) a[j] += __shfl_xor(a[j], off);
    if (eo == 0) {
        float dn = dinv[n];
        H8 o0, o1;
#pragma unroll
        for (int j = 0; j < 8; ++j) o0.h[j] = __float2half(a[j] * dn);
#pragma unroll
        for (int j = 0; j < 8; ++j) o1.h[j] = __float2half(a[8 + j] * dn);
        float4* op = reinterpret_cast<float4*>(hout + (size_t)n * 64 + q * 16);
        op[0] = o0.f4;
        op[1] = o1.f4;
    }
}

// F=16: 8 nodes per wave (8 lanes each); 2 lanes/row (16B); 4 edges in flight.
__global__ __launch_bounds__(256) void pull16h_kernel(const __half* __restrict__ hin,
                                                      const int* __restrict__ rowptr,
                                                      const int* __restrict__ ecol,
                                                      const float* __restrict__ dinv,
                                                      __half* __restrict__ hout) {
    int lane = threadIdx.x & 63;
    int q  = lane & 1;
    int eo = (lane >> 1) & 3;
    int g  = lane >> 3;
    int n = blockIdx.x * 32 + (threadIdx.x >> 6) * 8 + g;
    if (n >= Nn) return;
    int r0 = rowptr[n];
    int r1 = rowptr[n + 1];
    float a[8];
#pragma unroll
    for (int j = 0; j < 8; ++j) a[j] = 0.f;

    int e = r0 + eo;
    int s0 = (e < r1) ? ecol[e] : 0;
    float w0 = (e < r1) ? dinv[s0] : 0.f;
    int s1 = (e + 4 < r1) ? ecol[e + 4] : 0;
    float w1 = (e + 4 < r1) ? dinv[s1] : 0.f;
    float4 ga = *reinterpret_cast<const float4*>(hin + (size_t)s0 * 16 + q * 8);
#pragma unroll 1
    for (; e < r1; e += 4) {
        int s2 = (e + 8 < r1) ? ecol[e + 8] : 0;
        float w2 = (e + 8 < r1) ? dinv[s2] : 0.f;
        float4 na = *reinterpret_cast<const float4*>(hin + (size_t)s1 * 16 + q * 8);
        H8 u;
        u.f4 = ga;
#pragma unroll
        for (int j = 0; j < 8; ++j) a[j] += w0 * __half2float(u.h[j]);
        s1 = s2; w0 = w1; w1 = w2; ga = na;
    }
#pragma unroll
    for (int off = 2; off <= 4; off <<= 1)
#pragma unroll
        for (int j = 0; j < 8; ++j) a[j] += __shfl_xor(a[j], off);
    if (eo == 0) {
        float dn = dinv[n];
        H8 o;
#pragma unroll
        for (int j = 0; j < 8; ++j) o.h[j] = __float2half(a[j] * dn);
        *reinterpret_cast<float4*>(hout + (size_t)n * 16 + q * 8) = o.f4;
    }
}

// width-4 pull with fused add (f32 tables), 2-deep pipeline
template <int ADDBIAS>
__global__ __launch_bounds__(256) void pull4_kernel(const float* __restrict__ uin,
                                                    const float* __restrict__ gadd,
                                                    const int* __restrict__ rowptr,
                                                    const int* __restrict__ ecol,
                                                    const float* __restrict__ dinv,
                                                    const float* __restrict__ beff,
                                                    float* __restrict__ out) {
    int lane = threadIdx.x & 63;
    int eo = lane & 15;
    int n = blockIdx.x * 16 + ((threadIdx.x >> 6) << 2) + (lane >> 4);
    if (n >= Nn) return;
    int r0 = rowptr[n];
    int r1 = rowptr[n + 1];
    float ax = 0.f, ay = 0.f, az = 0.f, aw = 0.f;

    int e = r0 + eo;
    int s0 = (e < r1) ? ecol[e] : 0;
    float w0 = (e < r1) ? dinv[s0] : 0.f;
    int s1 = (e + 16 < r1) ? ecol[e + 16] : 0;
    float w1 = (e + 16 < r1) ? dinv[s1] : 0.f;
    float4 ga = *reinterpret_cast<const float4*>(uin + (size_t)s0 * 4);
#pragma unroll 1
    for (; e < r1; e += 16) {
        int s2 = (e + 32 < r1) ? ecol[e + 32] : 0;
        float w2 = (e + 32 < r1) ? dinv[s2] : 0.f;
        float4 na = *reinterpret_cast<const float4*>(uin + (size_t)s1 * 4);
        ax += w0 * ga.x;
        ay += w0 * ga.y;
        az += w0 * ga.z;
        aw += w0 * ga.w;
        s1 = s2; w0 = w1; w1 = w2; ga = na;
    }
#pragma unroll
    for (int off = 1; off < 16; off <<= 1) {
        ax += __shfl_xor(ax, off);
        ay += __shfl_xor(ay, off);
        az += __shfl_xor(az, off);
        aw += __shfl_xor(aw, off);
    }
    if (eo == 0) {
        float dn = dinv[n];
        float4 g = *reinterpret_cast<const float4*>(gadd + (size_t)n * 4);
        float4 o;
        o.x = g.x + dn * ax;
        o.y = g.y + dn * ay;
        o.z = g.z + dn * az;
        o.w = g.w + dn * aw;
        if (ADDBIAS) {
            o.x += beff[0]; o.y += beff[1]; o.z += beff[2]; o.w += beff[3];
        }
        *reinterpret_cast<float4*>(out + (size_t)n * 4) = o;
    }
}

// ================= weight fragment prep =================
template <int KS>
__global__ __launch_bounds__(256) void wfrag_kernel(const float* __restrict__ W,  // [4][KS][64]
                                                    __half* __restrict__ Wfrag) {
    constexpr int NT = (4 * KS / 32) * 4 * 64;
    int tid = blockIdx.x * 256 + threadIdx.x;
    if (tid >= NT) return;
    int l  = tid & 63;
    int ct = (tid >> 6) & 3;
    int ks = tid >> 8;
    int c  = ct * 16 + (l & 15);
    int kb = ks * 32 + (l >> 4) * 8;
    H8 o;
#pragma unroll
    for (int j = 0; j < 8; ++j) {
        int k = kb + j;
        o.h[j] = __float2half(W[(size_t)(k / KS) * KS * 64 + (size_t)(k % KS) * 64 + c]);
    }
    *reinterpret_cast<float4*>(Wfrag + (size_t)tid * 8) = o.f4;
}

// ================= fused 4-source MFMA GEMM =================
template <int KS, int RELU>
__global__ __launch_bounds__(256) void gemm4m_kernel(const __half* __restrict__ S0,
                                                     const __half* __restrict__ S1,
                                                     const __half* __restrict__ S2,
                                                     const __half* __restrict__ S3,
                                                     const __half* __restrict__ Wfrag,
                                                     const float* __restrict__ bias,
                                                     __half* __restrict__ out) {
    constexpr int NKS = 4 * KS / 32;  // K-steps of 32
    int lane = threadIdx.x & 63;
    int wv = threadIdx.x >> 6;
    int base = blockIdx.x * 128 + wv * 32;
    int r = lane & 15;
    int qa = lane >> 4;
    int acol = qa * 8;
    const __half* Ss[4] = {S0, S1, S2, S3};
    f32x4 acc[2][4] = {};
    int row0 = base + r;       if (row0 >= Nn) row0 = Nn - 1;
    int row1 = base + 16 + r;  if (row1 >= Nn) row1 = Nn - 1;
#pragma unroll
    for (int ks = 0; ks < NKS; ++ks) {
        int k0 = ks * 32 + acol;
        const __half* Sa = Ss[k0 / KS];
        int col = k0 % KS;
        f16x8 a0 = *reinterpret_cast<const f16x8*>(Sa + (size_t)row0 * KS + col);
        f16x8 a1 = *reinterpret_cast<const f16x8*>(Sa + (size_t)row1 * KS + col);
        const __half* wp = Wfrag + ((size_t)(ks * 4) * 64 + lane) * 8;
#pragma unroll
        for (int ct = 0; ct < 4; ++ct) {
            f16x8 b = *reinterpret_cast<const f16x8*>(wp + (size_t)ct * 64 * 8);
            acc[0][ct] = __builtin_amdgcn_mfma_f32_16x16x32_f16(a0, b, acc[0][ct], 0, 0, 0);
            acc[1][ct] = __builtin_amdgcn_mfma_f32_16x16x32_f16(a1, b, acc[1][ct], 0, 0, 0);
        }
    }
    int ccol = lane & 15;
    int rb = (lane >> 4) * 4;
#pragma unroll
    for (int rt = 0; rt < 2; ++rt) {
#pragma unroll
        for (int ct = 0; ct < 4; ++ct) {
            float bi = bias[ct * 16 + ccol];
#pragma unroll
            for (int i = 0; i < 4; ++i) {
                int row = base + rt * 16 + rb + i;
                if (row < Nn) {
                    float v = acc[rt][ct][i] + bi;
                    if (RELU) v = fmaxf(v, 0.f);
                    out[(size_t)row * 64 + ct * 16 + ccol] = __float2half(v);
                }
            }
        }
    }
}

// ================= last conv + FC folding =================
__global__ __launch_bounds__(256) void weff_kernel(const float* __restrict__ W,   // Wh[2]: [4][64][64]
                                                   const float* __restrict__ b,   // bh[2]: [64]
                                                   const float* __restrict__ fcW, // [64][4]
                                                   const float* __restrict__ fcb, // [4]
                                                   float* __restrict__ Wg,        // [4][64][4]
                                                   float* __restrict__ beff) {    // [4]
    int t = threadIdx.x;  // t = k*64 + c
    int k = t >> 6, c = t & 63;
    const float* wrow = W + (size_t)t * 64;
    float a0 = 0.f, a1 = 0.f, a2 = 0.f, a3 = 0.f;
    for (int d = 0; d < 64; ++d) {
        float w = wrow[d];
        a0 += w * fcW[d * 4 + 0];
        a1 += w * fcW[d * 4 + 1];
        a2 += w * fcW[d * 4 + 2];
        a3 += w * fcW[d * 4 + 3];
    }
    float4 o; o.x = a0; o.y = a1; o.z = a2; o.w = a3;
    *reinterpret_cast<float4*>(Wg + k * 256 + c * 4) = o;
    if (t < 4) {
        float s = fcb[t];
        for (int d = 0; d < 64; ++d) s += b[d] * fcW[d * 4 + t];
        beff[t] = s;
    }
}

// Gk[n][j] = sum_c h[n][c] * Wg[k][c][j]
__global__ __launch_bounds__(256) void gemmG_kernel(const __half* __restrict__ h,
                                                    const float* __restrict__ Wg,
                                                    float* __restrict__ G) {
    __shared__ float Ht[64 * 65];
    __shared__ float Wl[1024];
    int t = threadIdx.x;
    int r0 = blockIdx.x * 64;
    for (int i = t; i < 256; i += 256)
        *reinterpret_cast<float4*>(&Wl[i * 4]) = *reinterpret_cast<const float4*>(Wg + i * 4);
    for (int i = t; i < 64 * 8; i += 256) {
        int r = i >> 3;
        int c8 = i & 7;
        int row = r0 + r;
        float* hp = &Ht[r * 65 + c8 * 8];
        if (row < Nn) {
            H8 u;
            u.f4 = *reinterpret_cast<const float4*>(h + (size_t)row * 64 + c8 * 8);
#pragma unroll
            for (int j = 0; j < 8; ++j) hp[j] = __half2float(u.h[j]);
        } else {
#pragma unroll
            for (int j = 0; j < 8; ++j) hp[j] = 0.f;
        }
    }
    __syncthreads();
    int r = t & 63;
    int k = t >> 6;
    float a0 = 0.f, a1 = 0.f, a2 = 0.f, a3 = 0.f;
#pragma unroll 8
    for (int c = 0; c < 64; ++c) {
        float hv = Ht[r * 65 + c];
        const float* wp = &Wl[k * 256 + c * 4];
        a0 += hv * wp[0];
        a1 += hv * wp[1];
        a2 += hv * wp[2];
        a3 += hv * wp[3];
    }
    int row = r0 + r;
    if (row < Nn) {
        float4 o; o.x = a0; o.y = a1; o.z = a2; o.w = a3;
        *reinterpret_cast<float4*>(G + (size_t)k * Nn * 4 + (size_t)row * 4) = o;
    }
}

// ================= host driver =================

extern "C" void kernel_launch(void* const* d_in, const int* in_sizes, int n_in,
                              void* d_out, int out_size, void* d_ws, size_t ws_size,
                              hipStream_t stream) {
    const float* x   = (const float*)d_in[0];
    const int*   ei  = (const int*)d_in[1];   // [2, E] int32
    const float* W0  = (const float*)d_in[2]; // [4,16,64]
    const float* b0  = (const float*)d_in[3]; // [64]
    const float* Wh  = (const float*)d_in[4]; // [3,4,64,64]
    const float* bh  = (const float*)d_in[5]; // [3,64]
    const float* fcW = (const float*)d_in[6]; // [64,4]
    const float* fcb = (const float*)d_in[7]; // [4]
    float* out = (float*)d_out;

    const int* src = ei;
    const int* dst = ei + Ne;

    // ws layout:
    // rowptr[100004] | ecol[Ne] | ghist[305792] | bsum[512] | dinv[N] | Wg[1024] | beff[16]
    // | Wf0[4096]h | Wf1[16384]h | Wf2[16384]h | xh[N*16]h | H0..H3[N*64]h | G(6*N*4 f32)
    int*    rowptr = (int*)d_ws;
    int*    ecol   = rowptr + 100004;
    int*    ghist  = ecol + Ne;
    int*    bsum   = ghist + 305792;
    float*  dinv   = (float*)(bsum + 512);
    float*  Wg     = dinv + Nn;
    float*  beff   = Wg + 1024;
    __half* Wf0    = (__half*)(beff + 16);
    __half* Wf1    = Wf0 + 4096;
    __half* Wf2    = Wf1 + 16384;
    __half* xh     = Wf2 + 16384;
    __half* H0     = xh + (size_t)Nn * NF;
    __half* H1     = H0 + (size_t)Nn * HID;
    __half* H2     = H1 + (size_t)Nn * HID;
    __half* H3     = H2 + (size_t)Nn * HID;
    float*  G      = (float*)(H3 + (size_t)Nn * HID);
    float*  G0     = G + 0 * (size_t)Nn * 4;
    float*  G1     = G + 1 * (size_t)Nn * 4;
    float*  G2     = G + 2 * (size_t)Nn * 4;
    float*  G3     = G + 3 * (size_t)Nn * 4;
    float*  T      = G + 4 * (size_t)Nn * 4;
    float*  T2     = G + 5 * (size_t)Nn * 4;
    int2*   tmp    = (int2*)H2;   // 12.8 MB, dead after bcsr

    const int s1grid = (NS + 1023) / 1024;         // 299
    const int s3grid = (NS + 255) / 256;           // 1195
    const int p64grid = (Nn + 15) / 16;            // 6250
    const int p16grid = (Nn + 31) / 32;            // 3125
    const int ggrid  = (Nn + 127) / 128;           // 782
    const int qgrid  = (Nn + 15) / 16;             // 6250
    const int Ggrid  = (Nn + 63) / 64;             // 1563
    const int cgrid  = (Nn * NF / 4 + 255) / 256;

    // --- CSR build: bucket sort, no global atomics; 4B edge records ---
    bhist_kernel<<<NB1, 256, 0, stream>>>(dst, ghist);
    scan1g_kernel<<<s1grid, 256, 0, stream>>>(ghist, bsum);
    scan2g_kernel<<<1, 512, 0, stream>>>(bsum, s1grid);
    scan3g_kernel<<<s3grid, 256, 0, stream>>>(ghist, bsum);
    bscatter_kernel<<<NB1, 256, 0, stream>>>(src, dst, ghist, tmp);
    bcsr_kernel<<<NBUK, 256, 0, stream>>>(tmp, ghist, rowptr, dinv, ecol);
    weff_kernel<<<1, 256, 0, stream>>>(Wh + 2 * 4 * 64 * 64, bh + 2 * 64, fcW, fcb, Wg, beff);
    xcvt_kernel<<<cgrid, 256, 0, stream>>>(x, xh);
    wfrag_kernel<16><<<2, 256, 0, stream>>>(W0, Wf0);
    wfrag_kernel<64><<<8, 256, 0, stream>>>(Wh + 0 * 4 * 64 * 64, Wf1);
    wfrag_kernel<64><<<8, 256, 0, stream>>>(Wh + 1 * 4 * 64 * 64, Wf2);

    // --- conv0 (F=16 hops, relu) -> H0 ---
    pull16h_kernel<<<p16grid, 256, 0, stream>>>(xh, rowptr, ecol, dinv, H1);
    pull16h_kernel<<<p16grid, 256, 0, stream>>>(H1, rowptr, ecol, dinv, H2);
    pull16h_kernel<<<p16grid, 256, 0, stream>>>(H2, rowptr, ecol, dinv, H3);
    gemm4m_kernel<16, 1><<<ggrid, 256, 0, stream>>>(xh, H1, H2, H3, Wf0, b0, H0);

    // --- conv1, conv2 (relu) : H0 -> H0 ---
    for (int l = 0; l < 2; ++l) {
        pull64h_kernel<<<p64grid, 256, 0, stream>>>(H0, rowptr, ecol, dinv, H1);
        pull64h_kernel<<<p64grid, 256, 0, stream>>>(H1, rowptr, ecol, dinv, H2);
        pull64h_kernel<<<p64grid, 256, 0, stream>>>(H2, rowptr, ecol, dinv, H3);
        gemm4m_kernel<64, 1><<<ggrid, 256, 0, stream>>>(H0, H1, H2, H3,
                                                        (l == 0) ? Wf1 : Wf2,
                                                        bh + (size_t)l * HID, H0);
    }

    // --- conv3 + FC, folded to width 4 + Horner (f32 chain) ---
    // out = G0 + A(G1 + A(G2 + A*G3)) + beff
    gemmG_kernel<<<Ggrid, 256, 0, stream>>>(H0, Wg, G);
    pull4_kernel<0><<<qgrid, 256, 0, stream>>>(G3, G2, rowptr, ecol, dinv, beff, T);
    pull4_kernel<0><<<qgrid, 256, 0, stream>>>(T,  G1, rowptr, ecol, dinv, beff, T2);
    pull4_kernel<1><<<qgrid, 256, 0, stream>>>(T2, G0, rowptr, ecol, dinv, beff, out);
}

// Round 13
// 508.755 us; speedup vs baseline: 1.4733x; 1.0479x over previous
//
#include <hip/hip_runtime.h>
#include <hip/hip_fp16.h>

// Problem constants (match reference)
constexpr int Nn   = 100000;   // nodes
constexpr int Ne   = 1600000;  // edges
constexpr int NF   = 16;       // input features
constexpr int HID  = 64;
constexpr int NOUT = 4;

// Bucket-sort CSR build params
constexpr int NBUK  = 391;                     // dst>>8 buckets (99999>>8 = 390)
constexpr int CHUNK = 2048;                    // edges per phase-1 block
constexpr int NB1   = (Ne + CHUNK - 1) / CHUNK;  // 782
constexpr int NS    = NBUK * NB1;              // 305762 ghist entries
constexpr int STASH = 6144;                    // K2 LDS stash (48 KB)

union H8 { float4 f4; __half h[8]; };
union H4 { float2 f2; __half h[4]; };

typedef _Float16 f16x8 __attribute__((ext_vector_type(8)));
typedef float    f32x4 __attribute__((ext_vector_type(4)));

// ================= CSR build (atomic-free, 2-level bucket sort) =================

__global__ __launch_bounds__(256) void bhist_kernel(const int* __restrict__ dst,
                                                    int* __restrict__ ghist) {
    __shared__ int h[NBUK];
    int t = threadIdx.x;
    int b = blockIdx.x;
    for (int i = t; i < NBUK; i += 256) h[i] = 0;
    __syncthreads();
    int e0 = b * CHUNK;
    int e1 = (e0 + CHUNK < Ne) ? e0 + CHUNK : Ne;
    for (int e = e0 + t; e < e1; e += 256) atomicAdd(&h[dst[e] >> 8], 1);
    __syncthreads();
    for (int i = t; i < NBUK; i += 256) ghist[i * NB1 + b] = h[i];
}

__global__ __launch_bounds__(256) void scan1g_kernel(int* __restrict__ g,
                                                     int* __restrict__ bsum) {
    __shared__ int lds[256];
    int t = threadIdx.x;
    int base = blockIdx.x * 1024 + t * 4;
    int v0 = (base + 0 < NS) ? g[base + 0] : 0;
    int v1 = (base + 1 < NS) ? g[base + 1] : 0;
    int v2 = (base + 2 < NS) ? g[base + 2] : 0;
    int v3 = (base + 3 < NS) ? g[base + 3] : 0;
    lds[t] = v0 + v1 + v2 + v3;
    __syncthreads();
    for (int off = 1; off < 256; off <<= 1) {
        int a = lds[t];
        int b = (t >= off) ? lds[t - off] : 0;
        __syncthreads();
        lds[t] = a + b;
        __syncthreads();
    }
    int excl = (t > 0) ? lds[t - 1] : 0;
    if (base + 0 < NS) g[base + 0] = excl;
    if (base + 1 < NS) g[base + 1] = excl + v0;
    if (base + 2 < NS) g[base + 2] = excl + v0 + v1;
    if (base + 3 < NS) g[base + 3] = excl + v0 + v1 + v2;
    if (t == 255) bsum[blockIdx.x] = lds[255];
}

__global__ __launch_bounds__(512) void scan2g_kernel(int* __restrict__ bsum, int nb) {
    __shared__ int lds[512];
    int t = threadIdx.x;
    int v = (t < nb) ? bsum[t] : 0;
    lds[t] = v;
    __syncthreads();
    for (int off = 1; off < 512; off <<= 1) {
        int a = lds[t];
        int b = (t >= off) ? lds[t - off] : 0;
        __syncthreads();
        lds[t] = a + b;
        __syncthreads();
    }
    if (t < nb) bsum[t] = lds[t] - v;  // exclusive
}

__global__ __launch_bounds__(256) void scan3g_kernel(int* __restrict__ g,
                                                     const int* __restrict__ bsum) {
    int i = blockIdx.x * 256 + threadIdx.x;
    if (i < NS) g[i] += bsum[i >> 10];
}

__global__ __launch_bounds__(256) void bscatter_kernel(const int* __restrict__ src,
                                                       const int* __restrict__ dst,
                                                       const int* __restrict__ ghist,
                                                       int2* __restrict__ tmp) {
    __shared__ int hb[NBUK];
    __shared__ int cur[NBUK];
    int t = threadIdx.x;
    int b = blockIdx.x;
    for (int i = t; i < NBUK; i += 256) {
        hb[i] = ghist[i * NB1 + b];
        cur[i] = 0;
    }
    __syncthreads();
    int e0 = b * CHUNK;
    int e1 = (e0 + CHUNK < Ne) ? e0 + CHUNK : Ne;
    for (int e = e0 + t; e < e1; e += 256) {
        int d = dst[e];
        int s = src[e];
        int bin = d >> 8;
        int r = atomicAdd(&cur[bin], 1);
        tmp[hb[bin] + r] = make_int2(s, d);
    }
}

__global__ __launch_bounds__(256) void bcsr_kernel(const int2* __restrict__ tmp,
                                                   const int* __restrict__ ghist,
                                                   int* __restrict__ rowptr,
                                                   float* __restrict__ dinv,
                                                   int* __restrict__ colsrc) {
    __shared__ int2 stash[STASH];
    __shared__ int h[256];
    __shared__ int hs[256];
    __shared__ int cur[256];
    int t = threadIdx.x;
    int b = blockIdx.x;
    int lo = ghist[b * NB1];
    int hi = (b < NBUK - 1) ? ghist[(b + 1) * NB1] : Ne;
    int sz = hi - lo;
    h[t] = 0;
    cur[t] = 0;
    __syncthreads();
    for (int i = t; i < sz; i += 256) {
        int2 rec = tmp[lo + i];
        if (i < STASH) stash[i] = rec;
        atomicAdd(&h[rec.y & 255], 1);
    }
    __syncthreads();
    int myh = h[t];
    hs[t] = myh;
    __syncthreads();
    for (int off = 1; off < 256; off <<= 1) {
        int a = hs[t];
        int bb = (t >= off) ? hs[t - off] : 0;
        __syncthreads();
        hs[t] = a + bb;
        __syncthreads();
    }
    int excl = hs[t] - myh;
    __syncthreads();
    hs[t] = excl;
    int d = (b << 8) + t;
    if (d < Nn) {
        rowptr[d] = lo + excl;
        dinv[d] = (myh > 0) ? rsqrtf((float)myh) : 0.0f;
    }
    if (b == NBUK - 1 && t == 0) rowptr[Nn] = Ne;
    __syncthreads();
    for (int i = t; i < sz; i += 256) {
        int2 rec = (i < STASH) ? stash[i] : tmp[lo + i];
        int bin = rec.y & 255;
        int r = atomicAdd(&cur[bin], 1);
        colsrc[lo + hs[bin] + r] = rec.x;
    }
}

__global__ __launch_bounds__(256) void fill_kernel(const int* __restrict__ colsrc,
                                                   const float* __restrict__ dinv,
                                                   int2* __restrict__ edge2) {
    int e = blockIdx.x * 256 + threadIdx.x;
    if (e < Ne) {
        int s = colsrc[e];
        edge2[e] = make_int2(s, __float_as_int(dinv[s]));
    }
}

// x[N,16] f32 -> xh[N,16] fp16
__global__ __launch_bounds__(256) void xcvt_kernel(const float* __restrict__ x,
                                                   __half* __restrict__ xh) {
    int i = blockIdx.x * 256 + threadIdx.x;
    if (i < Nn * NF / 4) {
        float4 v = reinterpret_cast<const float4*>(x)[i];
        H4 o;
        o.h[0] = __float2half(v.x);
        o.h[1] = __float2half(v.y);
        o.h[2] = __float2half(v.z);
        o.h[3] = __float2half(v.w);
        reinterpret_cast<float2*>(xh)[i] = o.f2;
    }
}

// ================= pull-mode propagation (fp16 tables, f32 math) =================
// 2-deep software pipeline: edge record i+2 and row gather i+1 in flight while
// consuming edge i. Dummy slots gather row 0 with w=0 (harmless, L2-hot).

// F=64: 4 nodes per wave (16 lanes each); QL=4 lanes x 16 halves; EO=4 edges in flight.
__global__ __launch_bounds__(256) void pull64h_kernel(const __half* __restrict__ hin,
                                                      const int* __restrict__ rowptr,
                                                      const int2* __restrict__ edge2,
                                                      const float* __restrict__ dinv,
                                                      __half* __restrict__ hout) {
    int lane = threadIdx.x & 63;
    int q  = lane & 3;
    int eo = (lane >> 2) & 3;
    int g  = lane >> 4;
    int n = blockIdx.x * 16 + (threadIdx.x >> 6) * 4 + g;
    if (n >= Nn) return;
    int r0 = rowptr[n];
    int r1 = rowptr[n + 1];
    float a[16];
#pragma unroll
    for (int j = 0; j < 16; ++j) a[j] = 0.f;

    int e = r0 + eo;
    int2 ed0 = (e < r1) ? edge2[e] : make_int2(0, 0);
    int2 ed1 = (e + 4 < r1) ? edge2[e + 4] : make_int2(0, 0);
    const float4* rp0 = reinterpret_cast<const float4*>(hin + (size_t)ed0.x * 64 + q * 16);
    float4 ga = rp0[0], gb = rp0[1];
#pragma unroll 1
    for (; e < r1; e += 4) {
        int2 ed2 = (e + 8 < r1) ? edge2[e + 8] : make_int2(0, 0);
        const float4* rp1 = reinterpret_cast<const float4*>(hin + (size_t)ed1.x * 64 + q * 16);
        float4 na = rp1[0], nb = rp1[1];
        float w = __int_as_float(ed0.y);
        H8 u0, u1;
        u0.f4 = ga;
        u1.f4 = gb;
#pragma unroll
        for (int j = 0; j < 8; ++j) a[j] += w * __half2float(u0.h[j]);
#pragma unroll
        for (int j = 0; j < 8; ++j) a[8 + j] += w * __half2float(u1.h[j]);
        ed0 = ed1; ed1 = ed2; ga = na; gb = nb;
    }
#pragma unroll
    for (int off = 4; off <= 8; off <<= 1)
#pragma unroll
        for (int j = 0; j < 16; ++j) a[j] += __shfl_xor(a[j], off);
    if (eo == 0) {
        float dn = dinv[n];
        H8 o0, o1;
#pragma unroll
        for (int j = 0; j < 8; ++j) o0.h[j] = __float2half(a[j] * dn);
#pragma unroll
        for (int j = 0; j < 8; ++j) o1.h[j] = __float2half(a[8 + j] * dn);
        float4* op = reinterpret_cast<float4*>(hout + (size_t)n * 64 + q * 16);
        op[0] = o0.f4;
        op[1] = o1.f4;
    }
}

// F=16: 8 nodes per wave (8 lanes each); QL=2 lanes x 8 halves (16B); EO=4.
__global__ __launch_bounds__(256) void pull16h_kernel(const __half* __restrict__ hin,
                                                      const int* __restrict__ rowptr,
                                                      const int2* __restrict__ edge2,
                                                      const float* __restrict__ dinv,
                                                      __half* __restrict__ hout) {
    int lane = threadIdx.x & 63;
    int q  = lane & 1;
    int eo = (lane >> 1) & 3;
    int g  = lane >> 3;
    int n = blockIdx.x * 32 + (threadIdx.x >> 6) * 8 + g;
    if (n >= Nn) return;
    int r0 = rowptr[n];
    int r1 = rowptr[n + 1];
    float a[8];
#pragma unroll
    for (int j = 0; j < 8; ++j) a[j] = 0.f;

    int e = r0 + eo;
    int2 ed0 = (e < r1) ? edge2[e] : make_int2(0, 0);
    int2 ed1 = (e + 4 < r1) ? edge2[e + 4] : make_int2(0, 0);
    float4 ga = *reinterpret_cast<const float4*>(hin + (size_t)ed0.x * 16 + q * 8);
#pragma unroll 1
    for (; e < r1; e += 4) {
        int2 ed2 = (e + 8 < r1) ? edge2[e + 8] : make_int2(0, 0);
        float4 na = *reinterpret_cast<const float4*>(hin + (size_t)ed1.x * 16 + q * 8);
        float w = __int_as_float(ed0.y);
        H8 u;
        u.f4 = ga;
#pragma unroll
        for (int j = 0; j < 8; ++j) a[j] += w * __half2float(u.h[j]);
        ed0 = ed1; ed1 = ed2; ga = na;
    }
#pragma unroll
    for (int off = 2; off <= 4; off <<= 1)
#pragma unroll
        for (int j = 0; j < 8; ++j) a[j] += __shfl_xor(a[j], off);
    if (eo == 0) {
        float dn = dinv[n];
        H8 o;
#pragma unroll
        for (int j = 0; j < 8; ++j) o.h[j] = __float2half(a[j] * dn);
        *reinterpret_cast<float4*>(hout + (size_t)n * 16 + q * 8) = o.f4;
    }
}

// width-4 pull with fused add (f32 tables), 2-deep pipeline
template <int ADDBIAS>
__global__ __launch_bounds__(256) void pull4_kernel(const float* __restrict__ uin,
                                                    const float* __restrict__ gadd,
                                                    const int* __restrict__ rowptr,
                                                    const int2* __restrict__ edge2,
                                                    const float* __restrict__ dinv,
                                                    const float* __restrict__ beff,
                                                    float* __restrict__ out) {
    int lane = threadIdx.x & 63;
    int eo = lane & 15;
    int n = blockIdx.x * 16 + ((threadIdx.x >> 6) << 2) + (lane >> 4);
    if (n >= Nn) return;
    int r0 = rowptr[n];
    int r1 = rowptr[n + 1];
    float ax = 0.f, ay = 0.f, az = 0.f, aw = 0.f;

    int e = r0 + eo;
    int2 ed0 = (e < r1) ? edge2[e] : make_int2(0, 0);
    int2 ed1 = (e + 16 < r1) ? edge2[e + 16] : make_int2(0, 0);
    float4 ga = *reinterpret_cast<const float4*>(uin + (size_t)ed0.x * 4);
#pragma unroll 1
    for (; e < r1; e += 16) {
        int2 ed2 = (e + 32 < r1) ? edge2[e + 32] : make_int2(0, 0);
        float4 na = *reinterpret_cast<const float4*>(uin + (size_t)ed1.x * 4);
        float w = __int_as_float(ed0.y);
        ax += w * ga.x;
        ay += w * ga.y;
        az += w * ga.z;
        aw += w * ga.w;
        ed0 = ed1; ed1 = ed2; ga = na;
    }
#pragma unroll
    for (int off = 1; off < 16; off <<= 1) {
        ax += __shfl_xor(ax, off);
        ay += __shfl_xor(ay, off);
        az += __shfl_xor(az, off);
        aw += __shfl_xor(aw, off);
    }
    if (eo == 0) {
        float dn = dinv[n];
        float4 g = *reinterpret_cast<const float4*>(gadd + (size_t)n * 4);
        float4 o;
        o.x = g.x + dn * ax;
        o.y = g.y + dn * ay;
        o.z = g.z + dn * az;
        o.w = g.w + dn * aw;
        if (ADDBIAS) {
            o.x += beff[0]; o.y += beff[1]; o.z += beff[2]; o.w += beff[3];
        }
        *reinterpret_cast<float4*>(out + (size_t)n * 4) = o;
    }
}

// ================= weight fragment prep =================
template <int KS>
__global__ __launch_bounds__(256) void wfrag_kernel(const float* __restrict__ W,  // [4][KS][64]
                                                    __half* __restrict__ Wfrag) {
    constexpr int NT = (4 * KS / 32) * 4 * 64;
    int tid = blockIdx.x * 256 + threadIdx.x;
    if (tid >= NT) return;
    int l  = tid & 63;
    int ct = (tid >> 6) & 3;
    int ks = tid >> 8;
    int c  = ct * 16 + (l & 15);
    int kb = ks * 32 + (l >> 4) * 8;
    H8 o;
#pragma unroll
    for (int j = 0; j < 8; ++j) {
        int k = kb + j;
        o.h[j] = __float2half(W[(size_t)(k / KS) * KS * 64 + (size_t)(k % KS) * 64 + c]);
    }
    *reinterpret_cast<float4*>(Wfrag + (size_t)tid * 8) = o.f4;
}

// ================= fused 4-source MFMA GEMM =================
template <int KS, int RELU>
__global__ __launch_bounds__(256) void gemm4m_kernel(const __half* __restrict__ S0,
                                                     const __half* __restrict__ S1,
                                                     const __half* __restrict__ S2,
                                                     const __half* __restrict__ S3,
                                                     const __half* __restrict__ Wfrag,
                                                     const float* __restrict__ bias,
                                                     __half* __restrict__ out) {
    constexpr int NKS = 4 * KS / 32;  // K-steps of 32
    int lane = threadIdx.x & 63;
    int wv = threadIdx.x >> 6;
    int base = blockIdx.x * 128 + wv * 32;
    int r = lane & 15;
    int qa = lane >> 4;
    int acol = qa * 8;
    const __half* Ss[4] = {S0, S1, S2, S3};
    f32x4 acc[2][4] = {};
    int row0 = base + r;       if (row0 >= Nn) row0 = Nn - 1;
    int row1 = base + 16 + r;  if (row1 >= Nn) row1 = Nn - 1;
#pragma unroll
    for (int ks = 0; ks < NKS; ++ks) {
        int k0 = ks * 32 + acol;
        const __half* Sa = Ss[k0 / KS];
        int col = k0 % KS;
        f16x8 a0 = *reinterpret_cast<const f16x8*>(Sa + (size_t)row0 * KS + col);
        f16x8 a1 = *reinterpret_cast<const f16x8*>(Sa + (size_t)row1 * KS + col);
        const __half* wp = Wfrag + ((size_t)(ks * 4) * 64 + lane) * 8;
#pragma unroll
        for (int ct = 0; ct < 4; ++ct) {
            f16x8 b = *reinterpret_cast<const f16x8*>(wp + (size_t)ct * 64 * 8);
            acc[0][ct] = __builtin_amdgcn_mfma_f32_16x16x32_f16(a0, b, acc[0][ct], 0, 0, 0);
            acc[1][ct] = __builtin_amdgcn_mfma_f32_16x16x32_f16(a1, b, acc[1][ct], 0, 0, 0);
        }
    }
    int ccol = lane & 15;
    int rb = (lane >> 4) * 4;
#pragma unroll
    for (int rt = 0; rt < 2; ++rt) {
#pragma unroll
        for (int ct = 0; ct < 4; ++ct) {
            float bi = bias[ct * 16 + ccol];
#pragma unroll
            for (int i = 0; i < 4; ++i) {
                int row = base + rt * 16 + rb + i;
                if (row < Nn) {
                    float v = acc[rt][ct][i] + bi;
                    if (RELU) v = fmaxf(v, 0.f);
                    out[(size_t)row * 64 + ct * 16 + ccol] = __float2half(v);
                }
            }
        }
    }
}

// ================= last conv + FC folding =================
__global__ __launch_bounds__(256) void weff_kernel(const float* __restrict__ W,   // Wh[2]: [4][64][64]
                                                   const float* __restrict__ b,   // bh[2]: [64]
                                                   const float* __restrict__ fcW, // [64][4]
                                                   const float* __restrict__ fcb, // [4]
                                                   float* __restrict__ Wg,        // [4][64][4]
                                                   float* __restrict__ beff) {    // [4]
    int t = threadIdx.x;  // t = k*64 + c
    int k = t >> 6, c = t & 63;
    const float* wrow = W + (size_t)t * 64;
    float a0 = 0.f, a1 = 0.f, a2 = 0.f, a3 = 0.f;
    for (int d = 0; d < 64; ++d) {
        float w = wrow[d];
        a0 += w * fcW[d * 4 + 0];
        a1 += w * fcW[d * 4 + 1];
        a2 += w * fcW[d * 4 + 2];
        a3 += w * fcW[d * 4 + 3];
    }
    float4 o; o.x = a0; o.y = a1; o.z = a2; o.w = a3;
    *reinterpret_cast<float4*>(Wg + k * 256 + c * 4) = o;
    if (t < 4) {
        float s = fcb[t];
        for (int d = 0; d < 64; ++d) s += b[d] * fcW[d * 4 + t];
        beff[t] = s;
    }
}

// Gk[n][j] = sum_c h[n][c] * Wg[k][c][j]
__global__ __launch_bounds__(256) void gemmG_kernel(const __half* __restrict__ h,
                                                    const float* __restrict__ Wg,
                                                    float* __restrict__ G) {
    __shared__ float Ht[64 * 65];
    __shared__ float Wl[1024];
    int t = threadIdx.x;
    int r0 = blockIdx.x * 64;
    for (int i = t; i < 256; i += 256)
        *reinterpret_cast<float4*>(&Wl[i * 4]) = *reinterpret_cast<const float4*>(Wg + i * 4);
    for (int i = t; i < 64 * 8; i += 256) {
        int r = i >> 3;
        int c8 = i & 7;
        int row = r0 + r;
        float* hp = &Ht[r * 65 + c8 * 8];
        if (row < Nn) {
            H8 u;
            u.f4 = *reinterpret_cast<const float4*>(h + (size_t)row * 64 + c8 * 8);
#pragma unroll
            for (int j = 0; j < 8; ++j) hp[j] = __half2float(u.h[j]);
        } else {
#pragma unroll
            for (int j = 0; j < 8; ++j) hp[j] = 0.f;
        }
    }
    __syncthreads();
    int r = t & 63;
    int k = t >> 6;
    float a0 = 0.f, a1 = 0.f, a2 = 0.f, a3 = 0.f;
#pragma unroll 8
    for (int c = 0; c < 64; ++c) {
        float hv = Ht[r * 65 + c];
        const float* wp = &Wl[k * 256 + c * 4];
        a0 += hv * wp[0];
        a1 += hv * wp[1];
        a2 += hv * wp[2];
        a3 += hv * wp[3];
    }
    int row = r0 + r;
    if (row < Nn) {
        float4 o; o.x = a0; o.y = a1; o.z = a2; o.w = a3;
        *reinterpret_cast<float4*>(G + (size_t)k * Nn * 4 + (size_t)row * 4) = o;
    }
}

// ================= host driver =================

extern "C" void kernel_launch(void* const* d_in, const int* in_sizes, int n_in,
                              void* d_out, int out_size, void* d_ws, size_t ws_size,
                              hipStream_t stream) {
    const float* x   = (const float*)d_in[0];
    const int*   ei  = (const int*)d_in[1];   // [2, E] int32
    const float* W0  = (const float*)d_in[2]; // [4,16,64]
    const float* b0  = (const float*)d_in[3]; // [64]
    const float* Wh  = (const float*)d_in[4]; // [3,4,64,64]
    const float* bh  = (const float*)d_in[5]; // [3,64]
    const float* fcW = (const float*)d_in[6]; // [64,4]
    const float* fcb = (const float*)d_in[7]; // [4]
    float* out = (float*)d_out;

    const int* src = ei;
    const int* dst = ei + Ne;

    // ws layout:
    // rowptr[100004] | edge2[2E] | ghist[305792] | bsum[512] | dinv[N] | Wg[1024] | beff[16]
    // | Wf0[4096]h | Wf1[16384]h | Wf2[16384]h | xh[N*16]h | H0..H3[N*64]h | G(6*N*4 f32)
    int*    rowptr = (int*)d_ws;
    int2*   edge2  = (int2*)(rowptr + 100004);
    int*    ghist  = (int*)(rowptr + 100004 + 2 * Ne);
    int*    bsum   = ghist + 305792;
    float*  dinv   = (float*)(bsum + 512);
    float*  Wg     = dinv + Nn;
    float*  beff   = Wg + 1024;
    __half* Wf0    = (__half*)(beff + 16);
    __half* Wf1    = Wf0 + 4096;
    __half* Wf2    = Wf1 + 16384;
    __half* xh     = Wf2 + 16384;
    __half* H0     = xh + (size_t)Nn * NF;
    __half* H1     = H0 + (size_t)Nn * HID;
    __half* H2     = H1 + (size_t)Nn * HID;
    __half* H3     = H2 + (size_t)Nn * HID;
    float*  G      = (float*)(H3 + (size_t)Nn * HID);
    float*  G0     = G + 0 * (size_t)Nn * 4;
    float*  G1     = G + 1 * (size_t)Nn * 4;
    float*  G2     = G + 2 * (size_t)Nn * 4;
    float*  G3     = G + 3 * (size_t)Nn * 4;
    float*  T      = G + 4 * (size_t)Nn * 4;
    float*  T2     = G + 5 * (size_t)Nn * 4;
    int2*   tmp    = (int2*)H2;   // 12.8 MB, dead after bcsr
    int*    colsrc = (int*)H1;    // 6.4 MB, dead after fill

    const int egrid  = (Ne + 255) / 256;           // 6250
    const int s1grid = (NS + 1023) / 1024;         // 299
    const int s3grid = (NS + 255) / 256;           // 1195
    const int p64grid = (Nn + 15) / 16;            // 6250
    const int p16grid = (Nn + 31) / 32;            // 3125
    const int ggrid  = (Nn + 127) / 128;           // 782
    const int qgrid  = (Nn + 15) / 16;             // 6250
    const int Ggrid  = (Nn + 63) / 64;             // 1563
    const int cgrid  = (Nn * NF / 4 + 255) / 256;

    // --- CSR build: bucket sort, no global atomics ---
    bhist_kernel<<<NB1, 256, 0, stream>>>(dst, ghist);
    scan1g_kernel<<<s1grid, 256, 0, stream>>>(ghist, bsum);
    scan2g_kernel<<<1, 512, 0, stream>>>(bsum, s1grid);
    scan3g_kernel<<<s3grid, 256, 0, stream>>>(ghist, bsum);
    bscatter_kernel<<<NB1, 256, 0, stream>>>(src, dst, ghist, tmp);
    bcsr_kernel<<<NBUK, 256, 0, stream>>>(tmp, ghist, rowptr, dinv, colsrc);
    fill_kernel<<<egrid, 256, 0, stream>>>(colsrc, dinv, edge2);
    weff_kernel<<<1, 256, 0, stream>>>(Wh + 2 * 4 * 64 * 64, bh + 2 * 64, fcW, fcb, Wg, beff);
    xcvt_kernel<<<cgrid, 256, 0, stream>>>(x, xh);
    wfrag_kernel<16><<<2, 256, 0, stream>>>(W0, Wf0);
    wfrag_kernel<64><<<8, 256, 0, stream>>>(Wh + 0 * 4 * 64 * 64, Wf1);
    wfrag_kernel<64><<<8, 256, 0, stream>>>(Wh + 1 * 4 * 64 * 64, Wf2);

    // --- conv0 (F=16 hops, relu) -> H0 ---
    pull16h_kernel<<<p16grid, 256, 0, stream>>>(xh, rowptr, edge2, dinv, H1);
    pull16h_kernel<<<p16grid, 256, 0, stream>>>(H1, rowptr, edge2, dinv, H2);
    pull16h_kernel<<<p16grid, 256, 0, stream>>>(H2, rowptr, edge2, dinv, H3);
    gemm4m_kernel<16, 1><<<ggrid, 256, 0, stream>>>(xh, H1, H2, H3, Wf0, b0, H0);

    // --- conv1, conv2 (relu) : H0 -> H0 ---
    for (int l = 0; l < 2; ++l) {
        pull64h_kernel<<<p64grid, 256, 0, stream>>>(H0, rowptr, edge2, dinv, H1);
        pull64h_kernel<<<p64grid, 256, 0, stream>>>(H1, rowptr, edge2, dinv, H2);
        pull64h_kernel<<<p64grid, 256, 0, stream>>>(H2, rowptr, edge2, dinv, H3);
        gemm4m_kernel<64, 1><<<ggrid, 256, 0, stream>>>(H0, H1, H2, H3,
                                                        (l == 0) ? Wf1 : Wf2,
                                                        bh + (size_t)l * HID, H0);
    }

    // --- conv3 + FC, folded to width 4 + Horner (f32 chain) ---
    // out = G0 + A(G1 + A(G2 + A*G3)) + beff
    gemmG_kernel<<<Ggrid, 256, 0, stream>>>(H0, Wg, G);
    pull4_kernel<0><<<qgrid, 256, 0, stream>>>(G3, G2, rowptr, edge2, dinv, beff, T);
    pull4_kernel<0><<<qgrid, 256, 0, stream>>>(T,  G1, rowptr, edge2, dinv, beff, T2);
    pull4_kernel<1><<<qgrid, 256, 0, stream>>>(T2, G0, rowptr, edge2, dinv, beff, out);
}